// Round 1
// baseline (3656.631 us; speedup 1.0000x reference)
//
#include <hip/hip_runtime.h>
#include <cstdint>
#include <cstddef>

// ---------------------------------------------------------------------------
// FeatureWiseCrossAttentionLSTM: F=40, OF=8, OW=24, L=3, H=128, NH=4, G=5
// B=32, T=512.
// Plan:
//   prep:   fp32 weights -> bf16 W_cat [l][f][n(512)][k] (k: 0..127 = W_hh,
//           128..255 = W_ih), combined bias b_ih+b_hh.
//   lstm:   3 launches, 80 WGs = (feature, batch-half), 512 thr (8 waves).
//           W_cat register-resident as MFMA B-frags; per step:
//           stage x_t (prev layer h) to LDS, MFMA gates = [h|x]@W^T,
//           bias (+rank-1 x*w_ih0 for layer0), LDS roundtrip for gate
//           regrouping, fp32 c/h update, h -> LDS (bf16) + global h_seq.
//           h_seq single-buffered across layers (read-before-overwrite, same
//           thread touches same address).
//   gattn:  5x32 blocks: group MHA, mean folded before V/O projections.
//   final:  32 blocks: pooled MHA (query pos 0 only) + FC -> d_out.
// ---------------------------------------------------------------------------

#define NFEAT 40
#define TDIM  512
#define HDIM  128

typedef __bf16 bf16x8 __attribute__((ext_vector_type(8)));
typedef float floatx4 __attribute__((ext_vector_type(4)));

__device__ __forceinline__ float bf2f(unsigned short s) {
  union { unsigned u; float f; } v; v.u = ((unsigned)s) << 16; return v.f;
}
__device__ __forceinline__ unsigned short f2bf(float f) {
  union { float f; unsigned u; } v; v.f = f;
  unsigned u = v.u + 0x7fffu + ((v.u >> 16) & 1u);
  return (unsigned short)(u >> 16);
}
__device__ __forceinline__ float sigm(float x) { return 1.f / (1.f + __expf(-x)); }
__device__ __forceinline__ float tanh_fast(float x) {
  x = fminf(fmaxf(x, -15.f), 15.f);
  float e = __expf(-2.f * x);
  return (1.f - e) / (1.f + e);
}

// ---------------------------------------------------------------------------
// prep: build bf16 W_cat + combined bias
// W0  : [40][512][128]  (layer 0: W_hh only)
// W12 : [2][40][512][256] (layers 1,2: k<128 -> W_hh, k>=128 -> W_ih12)
// biasAll : [3][40][512] = b_ih + b_hh
// ---------------------------------------------------------------------------
__global__ void prep_kernel(const float* __restrict__ w_ih12,
                            const float* __restrict__ w_hh,
                            const float* __restrict__ b_ih,
                            const float* __restrict__ b_hh,
                            unsigned short* __restrict__ W0,
                            unsigned short* __restrict__ W12,
                            float* __restrict__ biasAll)
{
  const int N0  = NFEAT * 512 * 128;       // 2,621,440
  const int N12 = 2 * NFEAT * 512 * 256;   // 10,485,760
  const int NB  = 3 * NFEAT * 512;         // 61,440
  const int total = N0 + N12 + NB;
  for (int idx = blockIdx.x * blockDim.x + threadIdx.x; idx < total;
       idx += gridDim.x * blockDim.x) {
    if (idx < N0) {
      W0[idx] = f2bf(w_hh[idx]);  // layer0 block of w_hh is first N0 elems
    } else if (idx < N0 + N12) {
      int i  = idx - N0;
      int k2 = i & 255;
      int n  = (i >> 8) & 511;
      int fl = i >> 17;            // l1*40 + f
      int l1 = fl / NFEAT, f = fl - l1 * NFEAT;
      float v;
      if (k2 < 128)
        v = w_hh[((((size_t)(l1 + 1) * NFEAT + f) * 512) + n) * 128 + k2];
      else
        v = w_ih12[((((size_t)l1 * NFEAT + f) * 512) + n) * 128 + (k2 - 128)];
      W12[i] = f2bf(v);
    } else {
      int i = idx - N0 - N12;
      biasAll[i] = b_ih[i] + b_hh[i];
    }
  }
}

// ---------------------------------------------------------------------------
// LSTM layer kernel. Grid: 80 blocks = (f = bx>>1, half = bx&1). 512 threads.
// KDIM = 128 (layer0, A = h only; x enters as rank-1 x*w_ih0 in epilogue)
// KDIM = 256 (layers 1,2: A = [h | x_t])
// hseq layout: [f][t][b(32)][j(128)] bf16, read (prev layer) then overwritten
// by this layer at the same (f,t,b,j) by the same thread.
// ---------------------------------------------------------------------------
template <int KDIM, bool IS_L0>
__global__ __launch_bounds__(512, 2) void lstm_layer(
    const unsigned short* __restrict__ W,    // [40][512][KDIM] bf16
    const float* __restrict__ bias,          // [40][512]
    const float* __restrict__ xin,           // layer0: x (B,F,T) fp32
    const float* __restrict__ w0,            // layer0: w_ih0 (F,512) fp32
    unsigned short* __restrict__ hseq)
{
  constexpr int KT   = KDIM / 32;
  constexpr int KPAD = KDIM + 8;   // row stride pad: 2-way (free) LDS aliasing

  const int tid  = threadIdx.x;
  const int wave = tid >> 6;
  const int lane = tid & 63;
  const int f    = blockIdx.x >> 1;
  const int half = blockIdx.x & 1;

  __shared__ unsigned short A_lds[16][KPAD];     // A = [h | x_t] bf16
  __shared__ float gates_lds[16][516];           // stride 516 (mod 32 = 4)
  __shared__ float bias_lds[512];
  __shared__ float w0_lds[IS_L0 ? 512 : 1];
  __shared__ float xs_lds[16];

  // ---- register-resident B fragments (W_cat rows, gemm_bt pattern) ----
  const int ncol = wave * 64 + (lane & 15);
  const int kb   = (lane >> 4) * 8;
  bf16x8 bfrag[4][KT];
#pragma unroll
  for (int nt = 0; nt < 4; ++nt) {
    const int n = ncol + nt * 16;
#pragma unroll
    for (int kt = 0; kt < KT; ++kt) {
      bfrag[nt][kt] =
          *(const bf16x8*)(W + ((size_t)f * 512 + n) * KDIM + kt * 32 + kb);
    }
  }
  bias_lds[tid] = bias[f * 512 + tid];
  if constexpr (IS_L0) w0_lds[tid] = w0[f * 512 + tid];

  for (int idx = tid; idx < 16 * KPAD; idx += 512)
    ((unsigned short*)A_lds)[idx] = 0;   // h0 = 0

  float creg[4] = {0.f, 0.f, 0.f, 0.f};  // c0 = 0 (this thread's 4 elems)
  const int b_loc = tid >> 5;            // 0..15  (batch row within half)
  const int j0    = (tid & 31) * 4;      // 0..124 (hidden cols, 4 each)
  const int m     = lane & 15;
  const int row0  = (lane >> 4) * 4;

  const size_t hbase =
      (((size_t)f * TDIM) * 32 + (size_t)(half * 16 + b_loc)) * 128 + j0;

#pragma unroll 1
  for (int t = 0; t < TDIM; ++t) {
    // ---- stage x_t ----
    if constexpr (!IS_L0) {
      const uint2 xv = *(const uint2*)(hseq + hbase + (size_t)t * 4096);
      *(uint2*)&A_lds[b_loc][128 + j0] = xv;
    } else {
      if (tid < 16)
        xs_lds[tid] = xin[((size_t)(half * 16 + tid) * NFEAT + f) * TDIM + t];
    }
    __syncthreads();   // barrier 1: x staged, prev h visible

    // ---- MFMA: gates = A @ W^T ----
    floatx4 acc[4];
#pragma unroll
    for (int nt = 0; nt < 4; ++nt) acc[nt] = (floatx4){0.f, 0.f, 0.f, 0.f};
    bf16x8 afrag[KT];
#pragma unroll
    for (int kt = 0; kt < KT; ++kt)
      afrag[kt] = *(const bf16x8*)&A_lds[m][kt * 32 + kb];
#pragma unroll
    for (int nt = 0; nt < 4; ++nt)
#pragma unroll
      for (int kt = 0; kt < KT; ++kt)
        acc[nt] = __builtin_amdgcn_mfma_f32_16x16x32_bf16(
            afrag[kt], bfrag[nt][kt], acc[nt], 0, 0, 0);

    // ---- C -> gates LDS (+bias, +rank-1 x*w0 for layer0) ----
#pragma unroll
    for (int nt = 0; nt < 4; ++nt) {
      const int col = ncol + nt * 16;
      const float bv = bias_lds[col];
      float w0v = 0.f;
      if constexpr (IS_L0) w0v = w0_lds[col];
#pragma unroll
      for (int r = 0; r < 4; ++r) {
        float gv = acc[nt][r] + bv;
        if constexpr (IS_L0) gv += xs_lds[row0 + r] * w0v;
        gates_lds[row0 + r][col] = gv;
      }
    }
    __syncthreads();   // barrier 2: gates complete

    // ---- epilogue: c/h update (fp32), h -> LDS + global (bf16) ----
    floatx4 gi = *(const floatx4*)&gates_lds[b_loc][j0];
    floatx4 gf = *(const floatx4*)&gates_lds[b_loc][128 + j0];
    floatx4 gg = *(const floatx4*)&gates_lds[b_loc][256 + j0];
    floatx4 go = *(const floatx4*)&gates_lds[b_loc][384 + j0];
    unsigned short hb[4];
#pragma unroll
    for (int jj = 0; jj < 4; ++jj) {
      const float si = sigm(gi[jj]);
      const float sf = sigm(gf[jj]);
      const float so = sigm(go[jj]);
      const float tg = tanh_fast(gg[jj]);
      const float c  = sf * creg[jj] + si * tg;
      creg[jj] = c;
      hb[jj] = f2bf(so * tanh_fast(c));
    }
    uint2 hpack;
    hpack.x = ((unsigned)hb[1] << 16) | hb[0];
    hpack.y = ((unsigned)hb[3] << 16) | hb[2];
    *(uint2*)&A_lds[b_loc][j0] = hpack;                  // next-step h operand
    *(uint2*)(hseq + hbase + (size_t)t * 4096) = hpack;  // h_seq for next layer
    // no barrier needed here: next iteration's writes touch disjoint LDS
    // regions before barrier 1; gates reads above complete before any thread
    // passes next barrier 1.
  }
}

// ---------------------------------------------------------------------------
// Group attention: grid (G=5 x B=32) blocks, 128 threads.
// pooled[b][g][:] = mean_over_qp(MHA(feats)) with mean folded before V/O proj.
// ---------------------------------------------------------------------------
__global__ void gattn_kernel(const unsigned short* __restrict__ hseq,
                             const float* __restrict__ g_wqkv,
                             const float* __restrict__ g_bqkv,
                             const float* __restrict__ g_wo,
                             const float* __restrict__ g_bo,
                             float* __restrict__ pooled)
{
  const int tid = threadIdx.x;
  const int g = blockIdx.x >> 5;
  const int b = blockIdx.x & 31;

  __shared__ float feat[8][128];
  __shared__ float qkv[8][384];
  __shared__ float sc[4][8][8];
  __shared__ float colsum[4][8];
  __shared__ float poolin[128];

  for (int idx = tid; idx < 8 * 128; idx += 128) {
    int of = idx >> 7, j = idx & 127;
    int f = g * 8 + of;
    feat[of][j] = bf2f(hseq[(((size_t)f * TDIM + (TDIM - 1)) * 32 + b) * 128 + j]);
  }
  __syncthreads();
  for (int idx = tid; idx < 8 * 384; idx += 128) {
    int of = idx / 384, r = idx - of * 384;
    const float* wr = g_wqkv + ((size_t)g * 384 + r) * 128;
    float s = 0.f;
    for (int j = 0; j < 128; ++j) s += feat[of][j] * wr[j];
    qkv[of][r] = s + g_bqkv[g * 384 + r];
  }
  __syncthreads();
  for (int idx = tid; idx < 256; idx += 128) {
    int n = idx >> 6, qp = (idx >> 3) & 7, kp = idx & 7;
    float s = 0.f;
    for (int d = 0; d < 32; ++d)
      s += qkv[qp][n * 32 + d] * qkv[kp][128 + n * 32 + d];
    sc[n][qp][kp] = s * 0.17677669529663687f;  // 1/sqrt(32)
  }
  __syncthreads();
  if (tid < 32) {  // softmax per (n, qp) row
    int n = tid >> 3, qp = tid & 7;
    float mx = -1e30f;
    for (int kp = 0; kp < 8; ++kp) mx = fmaxf(mx, sc[n][qp][kp]);
    float e[8], sum = 0.f;
    for (int kp = 0; kp < 8; ++kp) { e[kp] = __expf(sc[n][qp][kp] - mx); sum += e[kp]; }
    float inv = 1.f / sum;
    for (int kp = 0; kp < 8; ++kp) sc[n][qp][kp] = e[kp] * inv;
  }
  __syncthreads();
  if (tid < 32) {  // fold mean over qp before V: colsum[n][kp] = sum_qp attn
    int n = tid >> 3, kp = tid & 7;
    float s = 0.f;
    for (int qp = 0; qp < 8; ++qp) s += sc[n][qp][kp];
    colsum[n][kp] = s;
  }
  __syncthreads();
  {
    int n = tid >> 5;
    float s = 0.f;
    for (int kp = 0; kp < 8; ++kp) s += colsum[n][kp] * qkv[kp][256 + tid];
    poolin[tid] = s;
  }
  __syncthreads();
  {
    const float* wr = g_wo + ((size_t)g * 128 + tid) * 128;
    float s = 0.f;
    for (int i = 0; i < 128; ++i) s += poolin[i] * wr[i];
    pooled[((size_t)b * 5 + g) * 128 + tid] = s * 0.125f + g_bo[g * 128 + tid];
  }
}

// ---------------------------------------------------------------------------
// Final attention (query position 0 only) + FC. Grid: 32 blocks, 192 threads.
// ---------------------------------------------------------------------------
__global__ void final_kernel(const float* __restrict__ pooled,
                             const float* __restrict__ f_wqkv,
                             const float* __restrict__ f_bqkv,
                             const float* __restrict__ f_wo,
                             const float* __restrict__ f_bo,
                             const float* __restrict__ fc_w,
                             const float* __restrict__ fc_b,
                             float* __restrict__ out)
{
  const int tid = threadIdx.x;  // 0..191
  const int b = blockIdx.x;

  __shared__ float P[5][128];
  __shared__ float q0[128];
  __shared__ float kbuf[5][128];
  __shared__ float vbuf[5][128];
  __shared__ float attn[4][5];
  __shared__ float ao[128];
  __shared__ float fin[128];

  for (int idx = tid; idx < 640; idx += 192) {
    int g = idx >> 7, j = idx & 127;
    P[g][j] = pooled[((size_t)b * 5 + g) * 128 + j];
  }
  __syncthreads();
  for (int idx = tid; idx < 1408; idx += 192) {
    int kind, pos, r;
    if (idx < 128)       { kind = 0; pos = 0;                 r = idx; }
    else if (idx < 768)  { kind = 1; pos = (idx - 128) >> 7;  r = (idx - 128) & 127; }
    else                 { kind = 2; pos = (idx - 768) >> 7;  r = (idx - 768) & 127; }
    const int wrow = kind * 128 + r;
    const float* wr = f_wqkv + (size_t)wrow * 128;
    const float* src = P[kind == 0 ? 0 : pos];
    float s = 0.f;
    for (int j = 0; j < 128; ++j) s += src[j] * wr[j];
    s += f_bqkv[wrow];
    if (kind == 0) q0[r] = s;
    else if (kind == 1) kbuf[pos][r] = s;
    else vbuf[pos][r] = s;
  }
  __syncthreads();
  if (tid < 20) {
    int n = tid / 5, kp = tid - n * 5;
    float s = 0.f;
    for (int d = 0; d < 32; ++d) s += q0[n * 32 + d] * kbuf[kp][n * 32 + d];
    attn[n][kp] = s * 0.17677669529663687f;
  }
  __syncthreads();
  if (tid < 4) {
    float mx = -1e30f;
    for (int kp = 0; kp < 5; ++kp) mx = fmaxf(mx, attn[tid][kp]);
    float sum = 0.f;
    for (int kp = 0; kp < 5; ++kp) { float e = __expf(attn[tid][kp] - mx); attn[tid][kp] = e; sum += e; }
    float inv = 1.f / sum;
    for (int kp = 0; kp < 5; ++kp) attn[tid][kp] *= inv;
  }
  __syncthreads();
  if (tid < 128) {
    int n = tid >> 5;
    float s = 0.f;
    for (int kp = 0; kp < 5; ++kp) s += attn[n][kp] * vbuf[kp][tid];
    ao[tid] = s;
  }
  __syncthreads();
  if (tid < 128) {
    const float* wr = f_wo + (size_t)tid * 128;
    float s = 0.f;
    for (int i = 0; i < 128; ++i) s += ao[i] * wr[i];
    fin[tid] = s + f_bo[tid];
  }
  __syncthreads();
  {
    const float* wr = fc_w + (size_t)tid * 128;
    float s = 0.f;
    for (int j = 0; j < 128; ++j) s += fin[j] * wr[j];
    out[(size_t)b * 192 + tid] = s + fc_b[tid];
  }
}

// ---------------------------------------------------------------------------
extern "C" void kernel_launch(void* const* d_in, const int* in_sizes, int n_in,
                              void* d_out, int out_size, void* d_ws, size_t ws_size,
                              hipStream_t stream)
{
  const float* x      = (const float*)d_in[0];
  const float* w_ih0  = (const float*)d_in[1];   // (40,512,1)
  const float* w_ih12 = (const float*)d_in[2];   // (2,40,512,128)
  const float* w_hh   = (const float*)d_in[3];   // (3,40,512,128)
  const float* b_ih   = (const float*)d_in[4];   // (3,40,512)
  const float* b_hh   = (const float*)d_in[5];
  const float* g_wqkv = (const float*)d_in[6];
  const float* g_bqkv = (const float*)d_in[7];
  const float* g_wo   = (const float*)d_in[8];
  const float* g_bo   = (const float*)d_in[9];
  const float* f_wqkv = (const float*)d_in[10];
  const float* f_bqkv = (const float*)d_in[11];
  const float* f_wo   = (const float*)d_in[12];
  const float* f_bo   = (const float*)d_in[13];
  const float* fc_w   = (const float*)d_in[14];
  const float* fc_b   = (const float*)d_in[15];

  // workspace carve-up (~194.3 MB total)
  unsigned short* W0   = (unsigned short*)d_ws;                 // 40*512*128 bf16
  unsigned short* W12  = W0 + (size_t)NFEAT * 512 * 128;        // 2*40*512*256 bf16
  float* biasAll       = (float*)(W12 + (size_t)2 * NFEAT * 512 * 256);  // 3*40*512
  unsigned short* hseq = (unsigned short*)(biasAll + 3 * NFEAT * 512);   // 40*512*32*128 bf16
  float* pooled        = (float*)(hseq + (size_t)NFEAT * TDIM * 32 * 128); // 32*5*128

  prep_kernel<<<4096, 256, 0, stream>>>(w_ih12, w_hh, b_ih, b_hh, W0, W12, biasAll);

  lstm_layer<128, true><<<80, 512, 0, stream>>>(W0, biasAll, x, w_ih0, hseq);
  lstm_layer<256, false><<<80, 512, 0, stream>>>(W12, biasAll + NFEAT * 512,
                                                 nullptr, nullptr, hseq);
  lstm_layer<256, false><<<80, 512, 0, stream>>>(W12 + (size_t)NFEAT * 512 * 256,
                                                 biasAll + 2 * NFEAT * 512,
                                                 nullptr, nullptr, hseq);

  gattn_kernel<<<160, 128, 0, stream>>>(hseq, g_wqkv, g_bqkv, g_wo, g_bo, pooled);
  final_kernel<<<32, 192, 0, stream>>>(pooled, f_wqkv, f_bqkv, f_wo, f_bo,
                                       fc_w, fc_b, (float*)d_out);
}

// Round 2
// 2966.800 us; speedup vs baseline: 1.2325x; 1.2325x over previous
//
#include <hip/hip_runtime.h>
#include <cstdint>
#include <cstddef>

// ---------------------------------------------------------------------------
// FeatureWiseCrossAttentionLSTM: F=40, OF=8, OW=24, L=3, H=128, NH=4, G=5
// B=32, T=512.
// R1 restructure of the LSTM step (R0 was latency-bound, 5700 cyc/step):
//   * wave w owns gate tiles {g*128 + w*16 .. +16} for all 4 gates g ->
//     MFMA C fragments feed the c/h update fully in-register (gates LDS
//     roundtrip + its 8-way bank conflicts + barrier 2 eliminated).
//   * A = [h | x_t] operand double-buffered in LDS -> ONE barrier per step.
//   * x_{t+3} prefetched two-deep in registers (no global latency on the
//     critical path; safe: threads are within 1 barrier of each other, reads
//     run 3 steps ahead of overwrites).
//   * bias/w0 in registers; layer 2 skips hseq stores except t=511.
// ---------------------------------------------------------------------------

#define NFEAT 40
#define TDIM  512
#define HDIM  128

typedef __bf16 bf16x8 __attribute__((ext_vector_type(8)));
typedef float floatx4 __attribute__((ext_vector_type(4)));

__device__ __forceinline__ float bf2f(unsigned short s) {
  union { unsigned u; float f; } v; v.u = ((unsigned)s) << 16; return v.f;
}
__device__ __forceinline__ unsigned short f2bf(float f) {
  union { float f; unsigned u; } v; v.f = f;
  unsigned u = v.u + 0x7fffu + ((v.u >> 16) & 1u);
  return (unsigned short)(u >> 16);
}
__device__ __forceinline__ float sigm(float x) { return 1.f / (1.f + __expf(-x)); }
__device__ __forceinline__ float tanh_fast(float x) {
  x = fminf(fmaxf(x, -15.f), 15.f);
  float e = __expf(-2.f * x);
  return (1.f - e) / (1.f + e);
}

// ---------------------------------------------------------------------------
// prep: build bf16 W_cat + combined bias
// W0  : [40][512][128]  (layer 0: W_hh only)
// W12 : [2][40][512][256] (layers 1,2: k<128 -> W_hh, k>=128 -> W_ih12)
// biasAll : [3][40][512] = b_ih + b_hh
// ---------------------------------------------------------------------------
__global__ void prep_kernel(const float* __restrict__ w_ih12,
                            const float* __restrict__ w_hh,
                            const float* __restrict__ b_ih,
                            const float* __restrict__ b_hh,
                            unsigned short* __restrict__ W0,
                            unsigned short* __restrict__ W12,
                            float* __restrict__ biasAll)
{
  const int N0  = NFEAT * 512 * 128;
  const int N12 = 2 * NFEAT * 512 * 256;
  const int NB  = 3 * NFEAT * 512;
  const int total = N0 + N12 + NB;
  for (int idx = blockIdx.x * blockDim.x + threadIdx.x; idx < total;
       idx += gridDim.x * blockDim.x) {
    if (idx < N0) {
      W0[idx] = f2bf(w_hh[idx]);
    } else if (idx < N0 + N12) {
      int i  = idx - N0;
      int k2 = i & 255;
      int n  = (i >> 8) & 511;
      int fl = i >> 17;
      int l1 = fl / NFEAT, f = fl - l1 * NFEAT;
      float v;
      if (k2 < 128)
        v = w_hh[((((size_t)(l1 + 1) * NFEAT + f) * 512) + n) * 128 + k2];
      else
        v = w_ih12[((((size_t)l1 * NFEAT + f) * 512) + n) * 128 + (k2 - 128)];
      W12[i] = f2bf(v);
    } else {
      int i = idx - N0 - N12;
      biasAll[i] = b_ih[i] + b_hh[i];
    }
  }
}

// ---------------------------------------------------------------------------
// LSTM layer. Grid: 80 blocks = (f = bx>>1, half = bx&1). 512 threads.
// KDIM=128 (layer0: A = h; x enters as rank-1 x*w_ih0 in epilogue)
// KDIM=256 (layers 1,2: A = [h | x_t])
// ---------------------------------------------------------------------------
template <int KDIM, bool IS_L0, bool IS_LAST>
__global__ __launch_bounds__(512, 2) void lstm_layer(
    const unsigned short* __restrict__ W,    // [40][512][KDIM] bf16
    const float* __restrict__ bias,          // [40][512]
    const float* __restrict__ xin,           // layer0 only: x (B,F,T) fp32
    const float* __restrict__ w0,            // layer0 only: w_ih0 (F,512)
    unsigned short* __restrict__ hseq)       // [40][512][32][128] bf16
{
  constexpr int KT   = KDIM / 32;
  constexpr int KPAD = KDIM + 8;   // row stride 264/136 shorts -> 2-way (free)

  const int tid   = threadIdx.x;
  const int wave  = tid >> 6;
  const int lane  = tid & 63;
  const int f     = blockIdx.x >> 1;
  const int half  = blockIdx.x & 1;
  const int m15   = lane & 15;
  const int q     = lane >> 4;     // 0..3
  const int kb    = q * 8;
  const int jcol  = wave * 16 + m15;       // this lane's hidden column
  const int b_loc = tid >> 5;              // staging row 0..15
  const int j0    = (tid & 31) * 4;        // staging cols (4 shorts)

  __shared__ unsigned short A[2][16][KPAD];  // [h(128) | x(128)] bf16
  __shared__ float xs[2][16];                // layer0 scalar x

  // ---- register-resident B fragments: wave w, gate g -> rows g*128+w*16+m15
  bf16x8 bfrag[4][KT];
  float bv[4], w0v[4];
#pragma unroll
  for (int g = 0; g < 4; ++g) {
    const int n = g * 128 + wave * 16 + m15;
#pragma unroll
    for (int kt = 0; kt < KT; ++kt)
      bfrag[g][kt] =
          *(const bf16x8*)(W + ((size_t)f * 512 + n) * KDIM + kt * 32 + kb);
    bv[g] = bias[f * 512 + n];
    if constexpr (IS_L0) w0v[g] = w0[f * 512 + n]; else w0v[g] = 0.f;
  }

  // ---- zero LDS (h0 = 0), then stage x_0 and prime the prefetch pipe ----
  for (int idx = tid; idx < 2 * 16 * KPAD; idx += 512)
    ((unsigned short*)A)[idx] = 0;
  __syncthreads();

  const size_t xgbase =
      (size_t)f * (TDIM * 32 * 128) + (size_t)(half * 16 + b_loc) * 128 + j0;
  const size_t xgbase0 =
      IS_L0 ? ((size_t)(half * 16 + (tid & 15)) * NFEAT + f) * TDIM : 0;

  uint2 xv0 = {0, 0}, xv1 = {0, 0};
  float xf0 = 0.f, xf1 = 0.f;
  if constexpr (!IS_L0) {
    uint2 x0 = *(const uint2*)(hseq + xgbase);
    *(uint2*)&A[0][b_loc][128 + j0] = x0;
    xv0 = *(const uint2*)(hseq + xgbase + (size_t)1 * 4096);
    xv1 = *(const uint2*)(hseq + xgbase + (size_t)2 * 4096);
  } else {
    if (tid < 16) {
      xs[0][tid] = xin[xgbase0 + 0];
      xf0 = xin[xgbase0 + 1];
      xf1 = xin[xgbase0 + 2];
    }
  }
  __syncthreads();

  float creg[4] = {0.f, 0.f, 0.f, 0.f};
  const size_t hgbase = (size_t)f * (TDIM * 32 * 128) +
                        (size_t)(half * 16 + q * 4) * 128 + jcol;

#pragma unroll 1
  for (int t = 0; t < TDIM; ++t) {
    const int cur = t & 1, nxt = cur ^ 1;

    // ---- A fragments for this step (h_{t-1} | x_t) ----
    bf16x8 af[KT];
#pragma unroll
    for (int kt = 0; kt < KT; ++kt)
      af[kt] = *(const bf16x8*)&A[cur][m15][kt * 32 + kb];

    // ---- stage x_{t+1} into A[nxt]; rotate 2-deep prefetch (t+3) ----
    const int tl = (t + 3 < TDIM) ? t + 3 : TDIM - 1;
    if constexpr (!IS_L0) {
      *(uint2*)&A[nxt][b_loc][128 + j0] = xv0;
      xv0 = xv1;
      xv1 = *(const uint2*)(hseq + xgbase + (size_t)tl * 4096);
    } else {
      if (tid < 16) {
        xs[nxt][tid] = xf0;
        xf0 = xf1;
        xf1 = xin[xgbase0 + tl];
      }
    }

    // ---- MFMA: this wave's 4 gate tiles over full K ----
    floatx4 acc[4];
#pragma unroll
    for (int g = 0; g < 4; ++g) acc[g] = (floatx4){0.f, 0.f, 0.f, 0.f};
#pragma unroll
    for (int g = 0; g < 4; ++g)
#pragma unroll
      for (int kt = 0; kt < KT; ++kt)
        acc[g] = __builtin_amdgcn_mfma_f32_16x16x32_bf16(
            af[kt], bfrag[g][kt], acc[g], 0, 0, 0);

    // ---- in-register epilogue: lane owns (b=q*4+r, j=jcol), all 4 gates ----
#pragma unroll
    for (int r = 0; r < 4; ++r) {
      float gi = acc[0][r] + bv[0];
      float gf = acc[1][r] + bv[1];
      float gg = acc[2][r] + bv[2];
      float go = acc[3][r] + bv[3];
      if constexpr (IS_L0) {
        const float xb = xs[cur][q * 4 + r];
        gi += xb * w0v[0]; gf += xb * w0v[1];
        gg += xb * w0v[2]; go += xb * w0v[3];
      }
      const float c = sigm(gf) * creg[r] + sigm(gi) * tanh_fast(gg);
      creg[r] = c;
      const unsigned short hb = f2bf(sigm(go) * tanh_fast(c));
      A[nxt][q * 4 + r][jcol] = hb;                       // next-step operand
      if (!IS_LAST || t == TDIM - 1)
        hseq[hgbase + (size_t)t * 4096 + r * 128] = hb;   // h_seq out
    }
    __syncthreads();   // single barrier: A[nxt] complete for step t+1
  }
}

// ---------------------------------------------------------------------------
// Group attention: grid (G=5 x B=32) blocks, 128 threads.
// pooled[b][g][:] = mean_over_qp(MHA(feats)) with mean folded before V/O proj.
// ---------------------------------------------------------------------------
__global__ void gattn_kernel(const unsigned short* __restrict__ hseq,
                             const float* __restrict__ g_wqkv,
                             const float* __restrict__ g_bqkv,
                             const float* __restrict__ g_wo,
                             const float* __restrict__ g_bo,
                             float* __restrict__ pooled)
{
  const int tid = threadIdx.x;
  const int g = blockIdx.x >> 5;
  const int b = blockIdx.x & 31;

  __shared__ float feat[8][128];
  __shared__ float qkv[8][384];
  __shared__ float sc[4][8][8];
  __shared__ float colsum[4][8];
  __shared__ float poolin[128];

  for (int idx = tid; idx < 8 * 128; idx += 128) {
    int of = idx >> 7, j = idx & 127;
    int f = g * 8 + of;
    feat[of][j] = bf2f(hseq[(((size_t)f * TDIM + (TDIM - 1)) * 32 + b) * 128 + j]);
  }
  __syncthreads();
  for (int idx = tid; idx < 8 * 384; idx += 128) {
    int of = idx / 384, r = idx - of * 384;
    const float* wr = g_wqkv + ((size_t)g * 384 + r) * 128;
    float s = 0.f;
    for (int j = 0; j < 128; ++j) s += feat[of][j] * wr[j];
    qkv[of][r] = s + g_bqkv[g * 384 + r];
  }
  __syncthreads();
  for (int idx = tid; idx < 256; idx += 128) {
    int n = idx >> 6, qp = (idx >> 3) & 7, kp = idx & 7;
    float s = 0.f;
    for (int d = 0; d < 32; ++d)
      s += qkv[qp][n * 32 + d] * qkv[kp][128 + n * 32 + d];
    sc[n][qp][kp] = s * 0.17677669529663687f;  // 1/sqrt(32)
  }
  __syncthreads();
  if (tid < 32) {
    int n = tid >> 3, qp = tid & 7;
    float mx = -1e30f;
    for (int kp = 0; kp < 8; ++kp) mx = fmaxf(mx, sc[n][qp][kp]);
    float e[8], sum = 0.f;
    for (int kp = 0; kp < 8; ++kp) { e[kp] = __expf(sc[n][qp][kp] - mx); sum += e[kp]; }
    float inv = 1.f / sum;
    for (int kp = 0; kp < 8; ++kp) sc[n][qp][kp] = e[kp] * inv;
  }
  __syncthreads();
  if (tid < 32) {
    int n = tid >> 3, kp = tid & 7;
    float s = 0.f;
    for (int qp = 0; qp < 8; ++qp) s += sc[n][qp][kp];
    colsum[n][kp] = s;
  }
  __syncthreads();
  {
    int n = tid >> 5;
    float s = 0.f;
    for (int kp = 0; kp < 8; ++kp) s += colsum[n][kp] * qkv[kp][256 + tid];
    poolin[tid] = s;
  }
  __syncthreads();
  {
    const float* wr = g_wo + ((size_t)g * 128 + tid) * 128;
    float s = 0.f;
    for (int i = 0; i < 128; ++i) s += poolin[i] * wr[i];
    pooled[((size_t)b * 5 + g) * 128 + tid] = s * 0.125f + g_bo[g * 128 + tid];
  }
}

// ---------------------------------------------------------------------------
// Final attention (query position 0 only) + FC. Grid: 32 blocks, 192 threads.
// ---------------------------------------------------------------------------
__global__ void final_kernel(const float* __restrict__ pooled,
                             const float* __restrict__ f_wqkv,
                             const float* __restrict__ f_bqkv,
                             const float* __restrict__ f_wo,
                             const float* __restrict__ f_bo,
                             const float* __restrict__ fc_w,
                             const float* __restrict__ fc_b,
                             float* __restrict__ out)
{
  const int tid = threadIdx.x;  // 0..191
  const int b = blockIdx.x;

  __shared__ float P[5][128];
  __shared__ float q0[128];
  __shared__ float kbuf[5][128];
  __shared__ float vbuf[5][128];
  __shared__ float attn[4][5];
  __shared__ float ao[128];
  __shared__ float fin[128];

  for (int idx = tid; idx < 640; idx += 192) {
    int g = idx >> 7, j = idx & 127;
    P[g][j] = pooled[((size_t)b * 5 + g) * 128 + j];
  }
  __syncthreads();
  for (int idx = tid; idx < 1408; idx += 192) {
    int kind, pos, r;
    if (idx < 128)       { kind = 0; pos = 0;                 r = idx; }
    else if (idx < 768)  { kind = 1; pos = (idx - 128) >> 7;  r = (idx - 128) & 127; }
    else                 { kind = 2; pos = (idx - 768) >> 7;  r = (idx - 768) & 127; }
    const int wrow = kind * 128 + r;
    const float* wr = f_wqkv + (size_t)wrow * 128;
    const float* src = P[kind == 0 ? 0 : pos];
    float s = 0.f;
    for (int j = 0; j < 128; ++j) s += src[j] * wr[j];
    s += f_bqkv[wrow];
    if (kind == 0) q0[r] = s;
    else if (kind == 1) kbuf[pos][r] = s;
    else vbuf[pos][r] = s;
  }
  __syncthreads();
  if (tid < 20) {
    int n = tid / 5, kp = tid - n * 5;
    float s = 0.f;
    for (int d = 0; d < 32; ++d) s += q0[n * 32 + d] * kbuf[kp][n * 32 + d];
    attn[n][kp] = s * 0.17677669529663687f;
  }
  __syncthreads();
  if (tid < 4) {
    float mx = -1e30f;
    for (int kp = 0; kp < 5; ++kp) mx = fmaxf(mx, attn[tid][kp]);
    float sum = 0.f;
    for (int kp = 0; kp < 5; ++kp) { float e = __expf(attn[tid][kp] - mx); attn[tid][kp] = e; sum += e; }
    float inv = 1.f / sum;
    for (int kp = 0; kp < 5; ++kp) attn[tid][kp] *= inv;
  }
  __syncthreads();
  if (tid < 128) {
    int n = tid >> 5;
    float s = 0.f;
    for (int kp = 0; kp < 5; ++kp) s += attn[n][kp] * vbuf[kp][tid];
    ao[tid] = s;
  }
  __syncthreads();
  if (tid < 128) {
    const float* wr = f_wo + (size_t)tid * 128;
    float s = 0.f;
    for (int i = 0; i < 128; ++i) s += ao[i] * wr[i];
    fin[tid] = s + f_bo[tid];
  }
  __syncthreads();
  {
    const float* wr = fc_w + (size_t)tid * 128;
    float s = 0.f;
    for (int j = 0; j < 128; ++j) s += fin[j] * wr[j];
    out[(size_t)b * 192 + tid] = s + fc_b[tid];
  }
}

// ---------------------------------------------------------------------------
extern "C" void kernel_launch(void* const* d_in, const int* in_sizes, int n_in,
                              void* d_out, int out_size, void* d_ws, size_t ws_size,
                              hipStream_t stream)
{
  const float* x      = (const float*)d_in[0];
  const float* w_ih0  = (const float*)d_in[1];
  const float* w_ih12 = (const float*)d_in[2];
  const float* w_hh   = (const float*)d_in[3];
  const float* b_ih   = (const float*)d_in[4];
  const float* b_hh   = (const float*)d_in[5];
  const float* g_wqkv = (const float*)d_in[6];
  const float* g_bqkv = (const float*)d_in[7];
  const float* g_wo   = (const float*)d_in[8];
  const float* g_bo   = (const float*)d_in[9];
  const float* f_wqkv = (const float*)d_in[10];
  const float* f_bqkv = (const float*)d_in[11];
  const float* f_wo   = (const float*)d_in[12];
  const float* f_bo   = (const float*)d_in[13];
  const float* fc_w   = (const float*)d_in[14];
  const float* fc_b   = (const float*)d_in[15];

  unsigned short* W0   = (unsigned short*)d_ws;
  unsigned short* W12  = W0 + (size_t)NFEAT * 512 * 128;
  float* biasAll       = (float*)(W12 + (size_t)2 * NFEAT * 512 * 256);
  unsigned short* hseq = (unsigned short*)(biasAll + 3 * NFEAT * 512);
  float* pooled        = (float*)(hseq + (size_t)NFEAT * TDIM * 32 * 128);

  prep_kernel<<<4096, 256, 0, stream>>>(w_ih12, w_hh, b_ih, b_hh, W0, W12, biasAll);

  lstm_layer<128, true,  false><<<80, 512, 0, stream>>>(W0, biasAll, x, w_ih0, hseq);
  lstm_layer<256, false, false><<<80, 512, 0, stream>>>(W12, biasAll + NFEAT * 512,
                                                        nullptr, nullptr, hseq);
  lstm_layer<256, false, true ><<<80, 512, 0, stream>>>(W12 + (size_t)NFEAT * 512 * 256,
                                                        biasAll + 2 * NFEAT * 512,
                                                        nullptr, nullptr, hseq);

  gattn_kernel<<<160, 128, 0, stream>>>(hseq, g_wqkv, g_bqkv, g_wo, g_bo, pooled);
  final_kernel<<<32, 192, 0, stream>>>(pooled, f_wqkv, f_bqkv, f_wo, f_bo,
                                       fc_w, fc_b, (float*)d_out);
}

// Round 3
// 1792.800 us; speedup vs baseline: 2.0396x; 1.6548x over previous
//
#include <hip/hip_runtime.h>
#include <cstdint>
#include <cstddef>

// ---------------------------------------------------------------------------
// FeatureWiseCrossAttentionLSTM: F=40, OF=8, OW=24, L=3, H=128, NH=4, G=5
// B=32, T=512.
// R3: transposed-MFMA recurrent step.
//   gates^T = W * [h|x]^T : W is the MFMA A operand, h^T/x^T the B operand.
//   - lane owns (batch=lane&15, j = wave*16 + quad*4 + r): epilogue fully
//     in-register, h written as ONE ds_write_b64 + ONE 8B global store.
//   - K split: h-part (K=128) on the critical path, W_hh frags resident
//     (64 VGPR). x-part (K=128) computes NEXT step's C-init (bias folded)
//     in the epilogue's shadow from global-prefetched x fragments (2 steps
//     ahead); x never goes through LDS.
//   - no IEEE divisions: v_rcp/v_exp based sigmoid/tanh.
//   - fragments stored as int4, bit_cast at the MFMA call.
// ---------------------------------------------------------------------------

#define NFEAT 40
#define TDIM  512
#define HDIM  128

typedef __bf16 bf16x8 __attribute__((ext_vector_type(8)));
typedef float floatx4 __attribute__((ext_vector_type(4)));
typedef int   intx4   __attribute__((ext_vector_type(4)));
typedef unsigned short u16;

#if __has_builtin(__builtin_amdgcn_exp2f)
#define EXP2F __builtin_amdgcn_exp2f
#else
#define EXP2F exp2f
#endif
#if __has_builtin(__builtin_amdgcn_rcpf)
#define RCPF __builtin_amdgcn_rcpf
#else
#define RCPF(x) (1.f / (x))
#endif

#define MF(a, b, c) __builtin_amdgcn_mfma_f32_16x16x32_bf16( \
    __builtin_bit_cast(bf16x8, (a)), __builtin_bit_cast(bf16x8, (b)), (c), 0, 0, 0)

__device__ __forceinline__ float bf2f(u16 s) {
  union { unsigned u; float f; } v; v.u = ((unsigned)s) << 16; return v.f;
}
__device__ __forceinline__ unsigned f2bf(float f) {
  union { float f; unsigned u; } v; v.f = f;
  unsigned u = v.u + 0x7fffu + ((v.u >> 16) & 1u);
  return (u >> 16);
}

// ---------------------------------------------------------------------------
// prep: straight fp32->bf16 converts (native layouts) + combined bias.
// Whh: [3][40][512][128] bf16 ; Wih: [2][40][512][128] bf16 ; biasAll [3][40][512]
// ---------------------------------------------------------------------------
__global__ void prep_kernel(const float* __restrict__ w_ih12,
                            const float* __restrict__ w_hh,
                            const float* __restrict__ b_ih,
                            const float* __restrict__ b_hh,
                            u16* __restrict__ Whh,
                            u16* __restrict__ Wih,
                            float* __restrict__ biasAll)
{
  const int N_hh = 3 * NFEAT * 512 * 128;   // 7,864,320
  const int N_ih = 2 * NFEAT * 512 * 128;   // 5,242,880
  const int NB   = 3 * NFEAT * 512;         // 61,440
  const int total = N_hh + N_ih + NB;
  for (int idx = blockIdx.x * blockDim.x + threadIdx.x; idx < total;
       idx += gridDim.x * blockDim.x) {
    if (idx < N_hh) {
      Whh[idx] = (u16)f2bf(w_hh[idx]);
    } else if (idx < N_hh + N_ih) {
      int i = idx - N_hh;
      Wih[i] = (u16)f2bf(w_ih12[i]);
    } else {
      int i = idx - N_hh - N_ih;
      biasAll[i] = b_ih[i] + b_hh[i];
    }
  }
}

// ---------------------------------------------------------------------------
// LSTM layer. Grid: 80 blocks = (f = bx>>1, half = bx&1). 512 threads.
// ---------------------------------------------------------------------------
template <bool IS_L0, bool IS_LAST>
__global__ __launch_bounds__(512, 2) void lstm_layer(
    const u16* __restrict__ Wh,      // [40][512][128] bf16 (this layer)
    const u16* __restrict__ Wx,      // [40][512][128] bf16 (L12; unused L0)
    const float* __restrict__ bias,  // [40][512] combined
    const float* __restrict__ xin,   // L0 only: x (B,F,T) fp32
    const float* __restrict__ w0,    // L0 only: w_ih0 (F,512) fp32
    u16* __restrict__ hseq)          // [40][512][32][128] bf16
{
  const int tid  = threadIdx.x;
  const int wave = tid >> 6;
  const int lane = tid & 63;
  const int m15  = lane & 15;        // B-operand col: batch ; A-operand row
  const int q    = lane >> 4;        // quad
  const int kb   = q * 8;            // k-offset within a 32-chunk (shorts)
  const int wq4  = wave * 16 + q * 4;  // this lane's first hidden column
  const int f    = blockIdx.x >> 1;
  const int half = blockIdx.x & 1;

  __shared__ __align__(16) u16 A[2][16][136];   // h operand, dbl-buffered

  // ---- resident W_hh fragments (A-operand): rows g*128 + wave*16 + m15 ----
  intx4 whf[4][4];
  const size_t wbase = (size_t)f * 512 * 128;
#pragma unroll
  for (int g = 0; g < 4; ++g)
#pragma unroll
    for (int kt = 0; kt < 4; ++kt)
      whf[g][kt] = *(const intx4*)(Wh + wbase +
          (size_t)(g * 128 + wave * 16 + m15) * 128 + kt * 32 + kb);

  // ---- resident W_ih fragments (L12) ----
  intx4 wxf[4][4];
  if constexpr (!IS_L0) {
#pragma unroll
    for (int g = 0; g < 4; ++g)
#pragma unroll
      for (int kt = 0; kt < 4; ++kt)
        wxf[g][kt] = *(const intx4*)(Wx + wbase +
            (size_t)(g * 128 + wave * 16 + m15) * 128 + kt * 32 + kb);
  }

  // ---- bias (C-init rows g*128 + wq4 + r) and w0 (L0) ----
  floatx4 bv[4], w0v[4];
#pragma unroll
  for (int g = 0; g < 4; ++g) {
    bv[g] = *(const floatx4*)(bias + f * 512 + g * 128 + wq4);
    if constexpr (IS_L0) w0v[g] = *(const floatx4*)(w0 + f * 512 + g * 128 + wq4);
  }

  // ---- zero A[0] (h_0 = 0) ----
  for (int idx = tid; idx < 16 * 136; idx += 512) ((u16*)A[0])[idx] = 0;
  __syncthreads();

  // ---- x pipeline primes ----
  const u16* xbase = hseq + (size_t)f * 512 * 4096 +
                     (size_t)(half * 16 + m15) * 128 + kb;   // L12 frag base
  const float* xsbase = IS_L0 ?
      (xin + (size_t)(half * 16 + m15) * (NFEAT * 512) + (size_t)f * 512) : nullptr;

  floatx4 accx0[4], accx1[4];
  intx4 xf0[4], xf1[4];
  float xsc[2] = {0.f, 0.f};
  const u16* xrd = xbase + (size_t)3 * 4096;
  const float* xsrd = IS_L0 ? (xsbase + 3) : nullptr;

  if constexpr (!IS_L0) {
    intx4 p0[4];
#pragma unroll
    for (int kt = 0; kt < 4; ++kt) p0[kt]  = *(const intx4*)(xbase + kt * 32);
#pragma unroll
    for (int kt = 0; kt < 4; ++kt) xf0[kt] = *(const intx4*)(xbase + 4096 + kt * 32);
#pragma unroll
    for (int kt = 0; kt < 4; ++kt) xf1[kt] = *(const intx4*)(xbase + 8192 + kt * 32);
#pragma unroll
    for (int g = 0; g < 4; ++g) {
      floatx4 a = bv[g];
#pragma unroll
      for (int kt = 0; kt < 4; ++kt) a = MF(wxf[g][kt], p0[kt], a);
      accx0[g] = a;
    }
  } else {
    const float x0 = xsbase[0];
    xsc[0] = xsbase[1];
    xsc[1] = xsbase[2];
#pragma unroll
    for (int g = 0; g < 4; ++g) accx0[g] = bv[g] + w0v[g] * x0;
  }

  float creg[4] = {0.f, 0.f, 0.f, 0.f};
  u16* hwr = hseq + (size_t)f * 512 * 4096 +
             (size_t)(half * 16 + m15) * 128 + wq4;

#define LSTM_STEP(PC, PN, ACC_C, ACC_N, XF_C, T)                               \
  {                                                                            \
    intx4 hf0 = *(const intx4*)&A[PC][m15][kb];                                \
    intx4 hf1 = *(const intx4*)&A[PC][m15][32 + kb];                           \
    intx4 hf2 = *(const intx4*)&A[PC][m15][64 + kb];                           \
    intx4 hf3 = *(const intx4*)&A[PC][m15][96 + kb];                           \
    floatx4 ac0 = MF(whf[0][0], hf0, ACC_C[0]);                                \
    floatx4 ac1 = MF(whf[1][0], hf0, ACC_C[1]);                                \
    floatx4 ac2 = MF(whf[2][0], hf0, ACC_C[2]);                                \
    floatx4 ac3 = MF(whf[3][0], hf0, ACC_C[3]);                                \
    ac0 = MF(whf[0][1], hf1, ac0); ac1 = MF(whf[1][1], hf1, ac1);              \
    ac2 = MF(whf[2][1], hf1, ac2); ac3 = MF(whf[3][1], hf1, ac3);              \
    ac0 = MF(whf[0][2], hf2, ac0); ac1 = MF(whf[1][2], hf2, ac1);              \
    ac2 = MF(whf[2][2], hf2, ac2); ac3 = MF(whf[3][2], hf2, ac3);              \
    ac0 = MF(whf[0][3], hf3, ac0); ac1 = MF(whf[1][3], hf3, ac1);              \
    ac2 = MF(whf[2][3], hf3, ac2); ac3 = MF(whf[3][3], hf3, ac3);              \
    /* x-group: next step's C-init (off critical path) */                      \
    if constexpr (!IS_L0) {                                                    \
      floatx4 n0 = bv[0], n1 = bv[1], n2 = bv[2], n3 = bv[3];                  \
      n0 = MF(wxf[0][0], XF_C[0], n0); n1 = MF(wxf[1][0], XF_C[0], n1);        \
      n2 = MF(wxf[2][0], XF_C[0], n2); n3 = MF(wxf[3][0], XF_C[0], n3);        \
      n0 = MF(wxf[0][1], XF_C[1], n0); n1 = MF(wxf[1][1], XF_C[1], n1);        \
      n2 = MF(wxf[2][1], XF_C[1], n2); n3 = MF(wxf[3][1], XF_C[1], n3);        \
      n0 = MF(wxf[0][2], XF_C[2], n0); n1 = MF(wxf[1][2], XF_C[2], n1);        \
      n2 = MF(wxf[2][2], XF_C[2], n2); n3 = MF(wxf[3][2], XF_C[2], n3);        \
      n0 = MF(wxf[0][3], XF_C[3], n0); n1 = MF(wxf[1][3], XF_C[3], n1);        \
      n2 = MF(wxf[2][3], XF_C[3], n2); n3 = MF(wxf[3][3], XF_C[3], n3);        \
      ACC_N[0] = n0; ACC_N[1] = n1; ACC_N[2] = n2; ACC_N[3] = n3;              \
      XF_C[0] = *(const intx4*)(xrd);                                          \
      XF_C[1] = *(const intx4*)(xrd + 32);                                     \
      XF_C[2] = *(const intx4*)(xrd + 64);                                     \
      XF_C[3] = *(const intx4*)(xrd + 96);                                     \
    } else {                                                                   \
      const float xn = xsc[PC];                                                \
      ACC_N[0] = bv[0] + w0v[0] * xn; ACC_N[1] = bv[1] + w0v[1] * xn;          \
      ACC_N[2] = bv[2] + w0v[2] * xn; ACC_N[3] = bv[3] + w0v[3] * xn;          \
      xsc[PC] = *xsrd;                                                         \
    }                                                                          \
    /* epilogue: lane owns batch m15, j = wq4 + r */                           \
    unsigned hlo, hhi;                                                         \
    {                                                                          \
      float hv[4];                                                             \
      _Pragma("unroll")                                                        \
      for (int r = 0; r < 4; ++r) {                                            \
        const float gi = ac0[r], gf = ac1[r], gg = ac2[r], go = ac3[r];        \
        const float si = RCPF(1.f + EXP2F(-1.44269504f * gi));                 \
        const float sf = RCPF(1.f + EXP2F(-1.44269504f * gf));                 \
        const float so = RCPF(1.f + EXP2F(-1.44269504f * go));                 \
        const float tg = 2.f * RCPF(1.f + EXP2F(-2.88539008f * gg)) - 1.f;     \
        const float c  = sf * creg[r] + si * tg;                               \
        creg[r] = c;                                                           \
        const float th = 2.f * RCPF(1.f + EXP2F(-2.88539008f * c)) - 1.f;      \
        hv[r] = so * th;                                                       \
      }                                                                        \
      hlo = (f2bf(hv[1]) << 16) | f2bf(hv[0]);                                 \
      hhi = (f2bf(hv[3]) << 16) | f2bf(hv[2]);                                 \
    }                                                                          \
    uint2 hp; hp.x = hlo; hp.y = hhi;                                          \
    *(uint2*)&A[PN][m15][wq4] = hp;                                            \
    if constexpr (IS_LAST) { if ((T) == TDIM - 1) *(uint2*)hwr = hp; }         \
    else                   { *(uint2*)hwr = hp; }                              \
    __syncthreads();                                                           \
  }

#pragma unroll 1
  for (int t = 0; t < TDIM; t += 2) {
    LSTM_STEP(0, 1, accx0, accx1, xf0, t);
    hwr += 4096;
    if constexpr (!IS_L0) { if (t + 4 < TDIM) xrd += 4096; }
    else                  { if (t + 4 < TDIM) xsrd += 1; }
    LSTM_STEP(1, 0, accx1, accx0, xf1, t + 1);
    hwr += 4096;
    if constexpr (!IS_L0) { if (t + 5 < TDIM) xrd += 4096; }
    else                  { if (t + 5 < TDIM) xsrd += 1; }
  }
#undef LSTM_STEP
}

// ---------------------------------------------------------------------------
// Group attention: grid (G=5 x B=32) blocks, 128 threads.
// ---------------------------------------------------------------------------
__global__ void gattn_kernel(const u16* __restrict__ hseq,
                             const float* __restrict__ g_wqkv,
                             const float* __restrict__ g_bqkv,
                             const float* __restrict__ g_wo,
                             const float* __restrict__ g_bo,
                             float* __restrict__ pooled)
{
  const int tid = threadIdx.x;
  const int g = blockIdx.x >> 5;
  const int b = blockIdx.x & 31;

  __shared__ float feat[8][128];
  __shared__ float qkv[8][384];
  __shared__ float sc[4][8][8];
  __shared__ float colsum[4][8];
  __shared__ float poolin[128];

  for (int idx = tid; idx < 8 * 128; idx += 128) {
    int of = idx >> 7, j = idx & 127;
    int f = g * 8 + of;
    feat[of][j] = bf2f(hseq[(((size_t)f * TDIM + (TDIM - 1)) * 32 + b) * 128 + j]);
  }
  __syncthreads();
  for (int idx = tid; idx < 8 * 384; idx += 128) {
    int of = idx / 384, r = idx - of * 384;
    const float* wr = g_wqkv + ((size_t)g * 384 + r) * 128;
    float s = 0.f;
    for (int j = 0; j < 128; ++j) s += feat[of][j] * wr[j];
    qkv[of][r] = s + g_bqkv[g * 384 + r];
  }
  __syncthreads();
  for (int idx = tid; idx < 256; idx += 128) {
    int n = idx >> 6, qp = (idx >> 3) & 7, kp = idx & 7;
    float s = 0.f;
    for (int d = 0; d < 32; ++d)
      s += qkv[qp][n * 32 + d] * qkv[kp][128 + n * 32 + d];
    sc[n][qp][kp] = s * 0.17677669529663687f;
  }
  __syncthreads();
  if (tid < 32) {
    int n = tid >> 3, qp = tid & 7;
    float mx = -1e30f;
    for (int kp = 0; kp < 8; ++kp) mx = fmaxf(mx, sc[n][qp][kp]);
    float e[8], sum = 0.f;
    for (int kp = 0; kp < 8; ++kp) { e[kp] = __expf(sc[n][qp][kp] - mx); sum += e[kp]; }
    float inv = 1.f / sum;
    for (int kp = 0; kp < 8; ++kp) sc[n][qp][kp] = e[kp] * inv;
  }
  __syncthreads();
  if (tid < 32) {
    int n = tid >> 3, kp = tid & 7;
    float s = 0.f;
    for (int qp = 0; qp < 8; ++qp) s += sc[n][qp][kp];
    colsum[n][kp] = s;
  }
  __syncthreads();
  {
    int n = tid >> 5;
    float s = 0.f;
    for (int kp = 0; kp < 8; ++kp) s += colsum[n][kp] * qkv[kp][256 + tid];
    poolin[tid] = s;
  }
  __syncthreads();
  {
    const float* wr = g_wo + ((size_t)g * 128 + tid) * 128;
    float s = 0.f;
    for (int i = 0; i < 128; ++i) s += poolin[i] * wr[i];
    pooled[((size_t)b * 5 + g) * 128 + tid] = s * 0.125f + g_bo[g * 128 + tid];
  }
}

// ---------------------------------------------------------------------------
// Final attention (query pos 0 only) + FC. Grid: 32 blocks, 192 threads.
// ---------------------------------------------------------------------------
__global__ void final_kernel(const float* __restrict__ pooled,
                             const float* __restrict__ f_wqkv,
                             const float* __restrict__ f_bqkv,
                             const float* __restrict__ f_wo,
                             const float* __restrict__ f_bo,
                             const float* __restrict__ fc_w,
                             const float* __restrict__ fc_b,
                             float* __restrict__ out)
{
  const int tid = threadIdx.x;
  const int b = blockIdx.x;

  __shared__ float P[5][128];
  __shared__ float q0[128];
  __shared__ float kbuf[5][128];
  __shared__ float vbuf[5][128];
  __shared__ float attn[4][5];
  __shared__ float ao[128];
  __shared__ float fin[128];

  for (int idx = tid; idx < 640; idx += 192) {
    int g = idx >> 7, j = idx & 127;
    P[g][j] = pooled[((size_t)b * 5 + g) * 128 + j];
  }
  __syncthreads();
  for (int idx = tid; idx < 1408; idx += 192) {
    int kind, pos, r;
    if (idx < 128)       { kind = 0; pos = 0;                 r = idx; }
    else if (idx < 768)  { kind = 1; pos = (idx - 128) >> 7;  r = (idx - 128) & 127; }
    else                 { kind = 2; pos = (idx - 768) >> 7;  r = (idx - 768) & 127; }
    const int wrow = kind * 128 + r;
    const float* wr = f_wqkv + (size_t)wrow * 128;
    const float* src = P[kind == 0 ? 0 : pos];
    float s = 0.f;
    for (int j = 0; j < 128; ++j) s += src[j] * wr[j];
    s += f_bqkv[wrow];
    if (kind == 0) q0[r] = s;
    else if (kind == 1) kbuf[pos][r] = s;
    else vbuf[pos][r] = s;
  }
  __syncthreads();
  if (tid < 20) {
    int n = tid / 5, kp = tid - n * 5;
    float s = 0.f;
    for (int d = 0; d < 32; ++d) s += q0[n * 32 + d] * kbuf[kp][n * 32 + d];
    attn[n][kp] = s * 0.17677669529663687f;
  }
  __syncthreads();
  if (tid < 4) {
    float mx = -1e30f;
    for (int kp = 0; kp < 5; ++kp) mx = fmaxf(mx, attn[tid][kp]);
    float sum = 0.f;
    for (int kp = 0; kp < 5; ++kp) { float e = __expf(attn[tid][kp] - mx); attn[tid][kp] = e; sum += e; }
    float inv = 1.f / sum;
    for (int kp = 0; kp < 5; ++kp) attn[tid][kp] *= inv;
  }
  __syncthreads();
  if (tid < 128) {
    int n = tid >> 5;
    float s = 0.f;
    for (int kp = 0; kp < 5; ++kp) s += attn[n][kp] * vbuf[kp][tid];
    ao[tid] = s;
  }
  __syncthreads();
  if (tid < 128) {
    const float* wr = f_wo + (size_t)tid * 128;
    float s = 0.f;
    for (int i = 0; i < 128; ++i) s += ao[i] * wr[i];
    fin[tid] = s + f_bo[tid];
  }
  __syncthreads();
  {
    const float* wr = fc_w + (size_t)tid * 128;
    float s = 0.f;
    for (int j = 0; j < 128; ++j) s += fin[j] * wr[j];
    out[(size_t)b * 192 + tid] = s + fc_b[tid];
  }
}

// ---------------------------------------------------------------------------
extern "C" void kernel_launch(void* const* d_in, const int* in_sizes, int n_in,
                              void* d_out, int out_size, void* d_ws, size_t ws_size,
                              hipStream_t stream)
{
  const float* x      = (const float*)d_in[0];
  const float* w_ih0  = (const float*)d_in[1];
  const float* w_ih12 = (const float*)d_in[2];
  const float* w_hh   = (const float*)d_in[3];
  const float* b_ih   = (const float*)d_in[4];
  const float* b_hh   = (const float*)d_in[5];
  const float* g_wqkv = (const float*)d_in[6];
  const float* g_bqkv = (const float*)d_in[7];
  const float* g_wo   = (const float*)d_in[8];
  const float* g_bo   = (const float*)d_in[9];
  const float* f_wqkv = (const float*)d_in[10];
  const float* f_bqkv = (const float*)d_in[11];
  const float* f_wo   = (const float*)d_in[12];
  const float* f_bo   = (const float*)d_in[13];
  const float* fc_w   = (const float*)d_in[14];
  const float* fc_b   = (const float*)d_in[15];

  const size_t N_hh = (size_t)3 * NFEAT * 512 * 128;
  const size_t N_ih = (size_t)2 * NFEAT * 512 * 128;
  const size_t NB   = (size_t)3 * NFEAT * 512;
  const size_t LSL  = (size_t)NFEAT * 512 * 128;   // per-layer weight slice

  u16* Whh       = (u16*)d_ws;
  u16* Wih       = Whh + N_hh;
  float* biasAll = (float*)(Wih + N_ih);
  u16* hseq      = (u16*)(biasAll + NB);
  float* pooled  = (float*)(hseq + (size_t)NFEAT * TDIM * 32 * 128);

  prep_kernel<<<2048, 256, 0, stream>>>(w_ih12, w_hh, b_ih, b_hh, Whh, Wih, biasAll);

  lstm_layer<true, false><<<80, 512, 0, stream>>>(
      Whh, Whh /*unused*/, biasAll, x, w_ih0, hseq);
  lstm_layer<false, false><<<80, 512, 0, stream>>>(
      Whh + LSL, Wih, biasAll + NFEAT * 512, nullptr, nullptr, hseq);
  lstm_layer<false, true><<<80, 512, 0, stream>>>(
      Whh + 2 * LSL, Wih + LSL, biasAll + 2 * NFEAT * 512, nullptr, nullptr, hseq);

  gattn_kernel<<<160, 128, 0, stream>>>(hseq, g_wqkv, g_bqkv, g_wo, g_bo, pooled);
  final_kernel<<<32, 192, 0, stream>>>(pooled, f_wqkv, f_bqkv, f_wo, f_bo,
                                       fc_w, fc_b, (float*)d_out);
}

// Round 4
// 1767.238 us; speedup vs baseline: 2.0691x; 1.0145x over previous
//
#include <hip/hip_runtime.h>
#include <cstdint>
#include <cstddef>

// ---------------------------------------------------------------------------
// FeatureWiseCrossAttentionLSTM: F=40, OF=8, OW=24, L=3, H=128, NH=4, G=5
// B=32, T=512.
// R4: barrier-drain fix on the R3 transposed-MFMA step.
//   __syncthreads drains vmcnt(0); R3 issued x-prefetch loads mid-step and
//   the global h-store right before the barrier -> every step paid a fresh
//   L3/HBM round-trip in the drain. Now:
//     - x_{t+3} fragments are loaded at the TOP of step t (2-step lead).
//     - global h-store is DEFERRED one step (store h_{t-1} at top of step t;
//       registers carry h across the barrier).
//   Everything else identical to R3.
// ---------------------------------------------------------------------------

#define NFEAT 40
#define TDIM  512
#define HDIM  128

typedef __bf16 bf16x8 __attribute__((ext_vector_type(8)));
typedef float floatx4 __attribute__((ext_vector_type(4)));
typedef int   intx4   __attribute__((ext_vector_type(4)));
typedef unsigned short u16;

#if __has_builtin(__builtin_amdgcn_exp2f)
#define EXP2F __builtin_amdgcn_exp2f
#else
#define EXP2F exp2f
#endif
#if __has_builtin(__builtin_amdgcn_rcpf)
#define RCPF __builtin_amdgcn_rcpf
#else
#define RCPF(x) (1.f / (x))
#endif

#define MF(a, b, c) __builtin_amdgcn_mfma_f32_16x16x32_bf16( \
    __builtin_bit_cast(bf16x8, (a)), __builtin_bit_cast(bf16x8, (b)), (c), 0, 0, 0)

__device__ __forceinline__ float bf2f(u16 s) {
  union { unsigned u; float f; } v; v.u = ((unsigned)s) << 16; return v.f;
}
__device__ __forceinline__ unsigned f2bf(float f) {
  union { float f; unsigned u; } v; v.f = f;
  unsigned u = v.u + 0x7fffu + ((v.u >> 16) & 1u);
  return (u >> 16);
}

// ---------------------------------------------------------------------------
// prep: straight fp32->bf16 converts (native layouts) + combined bias.
// ---------------------------------------------------------------------------
__global__ void prep_kernel(const float* __restrict__ w_ih12,
                            const float* __restrict__ w_hh,
                            const float* __restrict__ b_ih,
                            const float* __restrict__ b_hh,
                            u16* __restrict__ Whh,
                            u16* __restrict__ Wih,
                            float* __restrict__ biasAll)
{
  const int N_hh = 3 * NFEAT * 512 * 128;
  const int N_ih = 2 * NFEAT * 512 * 128;
  const int NB   = 3 * NFEAT * 512;
  const int total = N_hh + N_ih + NB;
  for (int idx = blockIdx.x * blockDim.x + threadIdx.x; idx < total;
       idx += gridDim.x * blockDim.x) {
    if (idx < N_hh) {
      Whh[idx] = (u16)f2bf(w_hh[idx]);
    } else if (idx < N_hh + N_ih) {
      int i = idx - N_hh;
      Wih[i] = (u16)f2bf(w_ih12[i]);
    } else {
      int i = idx - N_hh - N_ih;
      biasAll[i] = b_ih[i] + b_hh[i];
    }
  }
}

// ---------------------------------------------------------------------------
// LSTM layer. Grid: 80 blocks = (f = bx>>1, half = bx&1). 512 threads.
// ---------------------------------------------------------------------------
template <bool IS_L0, bool IS_LAST>
__global__ __launch_bounds__(512, 2) void lstm_layer(
    const u16* __restrict__ Wh,      // [40][512][128] bf16 (this layer)
    const u16* __restrict__ Wx,      // [40][512][128] bf16 (L12; unused L0)
    const float* __restrict__ bias,  // [40][512] combined
    const float* __restrict__ xin,   // L0 only: x (B,F,T) fp32
    const float* __restrict__ w0,    // L0 only: w_ih0 (F,512) fp32
    u16* __restrict__ hseq)          // [40][512][32][128] bf16
{
  const int tid  = threadIdx.x;
  const int wave = tid >> 6;
  const int lane = tid & 63;
  const int m15  = lane & 15;        // B-operand col: batch ; A-operand row
  const int q    = lane >> 4;        // quad
  const int kb   = q * 8;            // k-offset within a 32-chunk (shorts)
  const int wq4  = wave * 16 + q * 4;  // this lane's first hidden column
  const int f    = blockIdx.x >> 1;
  const int half = blockIdx.x & 1;

  __shared__ __align__(16) u16 A[2][16][136];   // h operand, dbl-buffered

  // ---- resident W_hh fragments (A-operand): rows g*128 + wave*16 + m15 ----
  intx4 whf[4][4];
  const size_t wbase = (size_t)f * 512 * 128;
#pragma unroll
  for (int g = 0; g < 4; ++g)
#pragma unroll
    for (int kt = 0; kt < 4; ++kt)
      whf[g][kt] = *(const intx4*)(Wh + wbase +
          (size_t)(g * 128 + wave * 16 + m15) * 128 + kt * 32 + kb);

  // ---- resident W_ih fragments (L12) ----
  intx4 wxf[4][4];
  if constexpr (!IS_L0) {
#pragma unroll
    for (int g = 0; g < 4; ++g)
#pragma unroll
      for (int kt = 0; kt < 4; ++kt)
        wxf[g][kt] = *(const intx4*)(Wx + wbase +
            (size_t)(g * 128 + wave * 16 + m15) * 128 + kt * 32 + kb);
  }

  // ---- bias (C-init rows g*128 + wq4 + r) and w0 (L0) ----
  floatx4 bv[4], w0v[4];
#pragma unroll
  for (int g = 0; g < 4; ++g) {
    bv[g] = *(const floatx4*)(bias + f * 512 + g * 128 + wq4);
    if constexpr (IS_L0) w0v[g] = *(const floatx4*)(w0 + f * 512 + g * 128 + wq4);
  }

  // ---- zero A[0] (h_0 = 0) ----
  for (int idx = tid; idx < 16 * 136; idx += 512) ((u16*)A[0])[idx] = 0;
  __syncthreads();

  // ---- x pipeline primes ----
  const u16* xbase = hseq + (size_t)f * 512 * 4096 +
                     (size_t)(half * 16 + m15) * 128 + kb;   // L12 frag base
  const float* xsbase = IS_L0 ?
      (xin + (size_t)(half * 16 + m15) * (NFEAT * 512) + (size_t)f * 512) : nullptr;

  floatx4 accx0[4], accx1[4];
  intx4 xf0[4], xf1[4];
  float xsc[2] = {0.f, 0.f};

  if constexpr (!IS_L0) {
    intx4 p0[4];
#pragma unroll
    for (int kt = 0; kt < 4; ++kt) p0[kt]  = *(const intx4*)(xbase + kt * 32);
#pragma unroll
    for (int kt = 0; kt < 4; ++kt) xf0[kt] = *(const intx4*)(xbase + 4096 + kt * 32);
#pragma unroll
    for (int kt = 0; kt < 4; ++kt) xf1[kt] = *(const intx4*)(xbase + 8192 + kt * 32);
#pragma unroll
    for (int g = 0; g < 4; ++g) {
      floatx4 a = bv[g];
#pragma unroll
      for (int kt = 0; kt < 4; ++kt) a = MF(wxf[g][kt], p0[kt], a);
      accx0[g] = a;
    }
  } else {
    const float x0 = xsbase[0];
    xsc[0] = xsbase[1];
    xsc[1] = xsbase[2];
#pragma unroll
    for (int g = 0; g < 4; ++g) accx0[g] = bv[g] + w0v[g] * x0;
  }

  float creg[4] = {0.f, 0.f, 0.f, 0.f};
  u16* hwr = hseq + (size_t)f * 512 * 4096 +
             (size_t)(half * 16 + m15) * 128 + wq4;   // slot t=0
  uint2 hdef;  // deferred h store (h_{t-1}), carried across the barrier

#define LSTM_STEP(PC, PN, ACC_C, ACC_N, XF_C, T)                               \
  {                                                                            \
    /* 0. deferred global h-store from the PREVIOUS step (long drain lead) */  \
    if constexpr (!IS_LAST) {                                                  \
      if ((T) > 0) *(uint2*)(hwr - 4096) = hdef;                               \
    }                                                                          \
    /* 1. x prefetch for t+3 into temps (early issue, ~2-step lead) */         \
    intx4 xn0, xn1, xn2, xn3;                                                  \
    float xns = 0.f;                                                           \
    {                                                                          \
      const int tl = ((T) + 3 < TDIM) ? (T) + 3 : TDIM - 1;                    \
      if constexpr (!IS_L0) {                                                  \
        const u16* xp = xbase + (size_t)tl * 4096;                             \
        xn0 = *(const intx4*)(xp);                                             \
        xn1 = *(const intx4*)(xp + 32);                                        \
        xn2 = *(const intx4*)(xp + 64);                                        \
        xn3 = *(const intx4*)(xp + 96);                                        \
      } else {                                                                 \
        xns = xsbase[tl];                                                      \
      }                                                                        \
    }                                                                          \
    /* 2. h fragments from LDS */                                              \
    intx4 hf0 = *(const intx4*)&A[PC][m15][kb];                                \
    intx4 hf1 = *(const intx4*)&A[PC][m15][32 + kb];                           \
    intx4 hf2 = *(const intx4*)&A[PC][m15][64 + kb];                           \
    intx4 hf3 = *(const intx4*)&A[PC][m15][96 + kb];                           \
    /* 3. h-MFMA (critical path) */                                            \
    floatx4 ac0 = MF(whf[0][0], hf0, ACC_C[0]);                                \
    floatx4 ac1 = MF(whf[1][0], hf0, ACC_C[1]);                                \
    floatx4 ac2 = MF(whf[2][0], hf0, ACC_C[2]);                                \
    floatx4 ac3 = MF(whf[3][0], hf0, ACC_C[3]);                                \
    ac0 = MF(whf[0][1], hf1, ac0); ac1 = MF(whf[1][1], hf1, ac1);              \
    ac2 = MF(whf[2][1], hf1, ac2); ac3 = MF(whf[3][1], hf1, ac3);              \
    ac0 = MF(whf[0][2], hf2, ac0); ac1 = MF(whf[1][2], hf2, ac1);              \
    ac2 = MF(whf[2][2], hf2, ac2); ac3 = MF(whf[3][2], hf2, ac3);              \
    ac0 = MF(whf[0][3], hf3, ac0); ac1 = MF(whf[1][3], hf3, ac1);              \
    ac2 = MF(whf[2][3], hf3, ac2); ac3 = MF(whf[3][3], hf3, ac3);              \
    /* 4. x-group: next step's C-init (off critical path), then rotate */      \
    if constexpr (!IS_L0) {                                                    \
      floatx4 n0 = bv[0], n1 = bv[1], n2 = bv[2], n3 = bv[3];                  \
      n0 = MF(wxf[0][0], XF_C[0], n0); n1 = MF(wxf[1][0], XF_C[0], n1);        \
      n2 = MF(wxf[2][0], XF_C[0], n2); n3 = MF(wxf[3][0], XF_C[0], n3);        \
      n0 = MF(wxf[0][1], XF_C[1], n0); n1 = MF(wxf[1][1], XF_C[1], n1);        \
      n2 = MF(wxf[2][1], XF_C[1], n2); n3 = MF(wxf[3][1], XF_C[1], n3);        \
      n0 = MF(wxf[0][2], XF_C[2], n0); n1 = MF(wxf[1][2], XF_C[2], n1);        \
      n2 = MF(wxf[2][2], XF_C[2], n2); n3 = MF(wxf[3][2], XF_C[2], n3);        \
      n0 = MF(wxf[0][3], XF_C[3], n0); n1 = MF(wxf[1][3], XF_C[3], n1);        \
      n2 = MF(wxf[2][3], XF_C[3], n2); n3 = MF(wxf[3][3], XF_C[3], n3);        \
      ACC_N[0] = n0; ACC_N[1] = n1; ACC_N[2] = n2; ACC_N[3] = n3;              \
      XF_C[0] = xn0; XF_C[1] = xn1; XF_C[2] = xn2; XF_C[3] = xn3;              \
    } else {                                                                   \
      const float xn = xsc[PC];                                                \
      ACC_N[0] = bv[0] + w0v[0] * xn; ACC_N[1] = bv[1] + w0v[1] * xn;          \
      ACC_N[2] = bv[2] + w0v[2] * xn; ACC_N[3] = bv[3] + w0v[3] * xn;          \
      xsc[PC] = xns;                                                           \
    }                                                                          \
    /* 5. epilogue: lane owns batch m15, j = wq4 + r */                        \
    unsigned hlo, hhi;                                                         \
    {                                                                          \
      float hv[4];                                                             \
      _Pragma("unroll")                                                        \
      for (int r = 0; r < 4; ++r) {                                            \
        const float gi = ac0[r], gf = ac1[r], gg = ac2[r], go = ac3[r];        \
        const float si = RCPF(1.f + EXP2F(-1.44269504f * gi));                 \
        const float sf = RCPF(1.f + EXP2F(-1.44269504f * gf));                 \
        const float so = RCPF(1.f + EXP2F(-1.44269504f * go));                 \
        const float tg = 2.f * RCPF(1.f + EXP2F(-2.88539008f * gg)) - 1.f;     \
        const float c  = sf * creg[r] + si * tg;                               \
        creg[r] = c;                                                           \
        const float th = 2.f * RCPF(1.f + EXP2F(-2.88539008f * c)) - 1.f;      \
        hv[r] = so * th;                                                       \
      }                                                                        \
      hlo = (f2bf(hv[1]) << 16) | f2bf(hv[0]);                                 \
      hhi = (f2bf(hv[3]) << 16) | f2bf(hv[2]);                                 \
    }                                                                          \
    uint2 hp; hp.x = hlo; hp.y = hhi;                                          \
    *(uint2*)&A[PN][m15][wq4] = hp;                                            \
    hdef = hp;                                                                 \
    hwr += 4096;                                                               \
    __syncthreads();                                                           \
  }

#pragma unroll 1
  for (int t = 0; t < TDIM; t += 2) {
    LSTM_STEP(0, 1, accx0, accx1, xf0, t);
    LSTM_STEP(1, 0, accx1, accx0, xf1, t + 1);
  }
#undef LSTM_STEP

  // final h (t = 511) store for all layer variants
  *(uint2*)(hwr - 4096) = hdef;
}

// ---------------------------------------------------------------------------
// Group attention: grid (G=5 x B=32) blocks, 128 threads.
// ---------------------------------------------------------------------------
__global__ void gattn_kernel(const u16* __restrict__ hseq,
                             const float* __restrict__ g_wqkv,
                             const float* __restrict__ g_bqkv,
                             const float* __restrict__ g_wo,
                             const float* __restrict__ g_bo,
                             float* __restrict__ pooled)
{
  const int tid = threadIdx.x;
  const int g = blockIdx.x >> 5;
  const int b = blockIdx.x & 31;

  __shared__ float feat[8][128];
  __shared__ float qkv[8][384];
  __shared__ float sc[4][8][8];
  __shared__ float colsum[4][8];
  __shared__ float poolin[128];

  for (int idx = tid; idx < 8 * 128; idx += 128) {
    int of = idx >> 7, j = idx & 127;
    int f = g * 8 + of;
    feat[of][j] = bf2f(hseq[(((size_t)f * TDIM + (TDIM - 1)) * 32 + b) * 128 + j]);
  }
  __syncthreads();
  for (int idx = tid; idx < 8 * 384; idx += 128) {
    int of = idx / 384, r = idx - of * 384;
    const float* wr = g_wqkv + ((size_t)g * 384 + r) * 128;
    float s = 0.f;
    for (int j = 0; j < 128; ++j) s += feat[of][j] * wr[j];
    qkv[of][r] = s + g_bqkv[g * 384 + r];
  }
  __syncthreads();
  for (int idx = tid; idx < 256; idx += 128) {
    int n = idx >> 6, qp = (idx >> 3) & 7, kp = idx & 7;
    float s = 0.f;
    for (int d = 0; d < 32; ++d)
      s += qkv[qp][n * 32 + d] * qkv[kp][128 + n * 32 + d];
    sc[n][qp][kp] = s * 0.17677669529663687f;
  }
  __syncthreads();
  if (tid < 32) {
    int n = tid >> 3, qp = tid & 7;
    float mx = -1e30f;
    for (int kp = 0; kp < 8; ++kp) mx = fmaxf(mx, sc[n][qp][kp]);
    float e[8], sum = 0.f;
    for (int kp = 0; kp < 8; ++kp) { e[kp] = __expf(sc[n][qp][kp] - mx); sum += e[kp]; }
    float inv = 1.f / sum;
    for (int kp = 0; kp < 8; ++kp) sc[n][qp][kp] = e[kp] * inv;
  }
  __syncthreads();
  if (tid < 32) {
    int n = tid >> 3, kp = tid & 7;
    float s = 0.f;
    for (int qp = 0; qp < 8; ++qp) s += sc[n][qp][kp];
    colsum[n][kp] = s;
  }
  __syncthreads();
  {
    int n = tid >> 5;
    float s = 0.f;
    for (int kp = 0; kp < 8; ++kp) s += colsum[n][kp] * qkv[kp][256 + tid];
    poolin[tid] = s;
  }
  __syncthreads();
  {
    const float* wr = g_wo + ((size_t)g * 128 + tid) * 128;
    float s = 0.f;
    for (int i = 0; i < 128; ++i) s += poolin[i] * wr[i];
    pooled[((size_t)b * 5 + g) * 128 + tid] = s * 0.125f + g_bo[g * 128 + tid];
  }
}

// ---------------------------------------------------------------------------
// Final attention (query pos 0 only) + FC. Grid: 32 blocks, 192 threads.
// ---------------------------------------------------------------------------
__global__ void final_kernel(const float* __restrict__ pooled,
                             const float* __restrict__ f_wqkv,
                             const float* __restrict__ f_bqkv,
                             const float* __restrict__ f_wo,
                             const float* __restrict__ f_bo,
                             const float* __restrict__ fc_w,
                             const float* __restrict__ fc_b,
                             float* __restrict__ out)
{
  const int tid = threadIdx.x;
  const int b = blockIdx.x;

  __shared__ float P[5][128];
  __shared__ float q0[128];
  __shared__ float kbuf[5][128];
  __shared__ float vbuf[5][128];
  __shared__ float attn[4][5];
  __shared__ float ao[128];
  __shared__ float fin[128];

  for (int idx = tid; idx < 640; idx += 192) {
    int g = idx >> 7, j = idx & 127;
    P[g][j] = pooled[((size_t)b * 5 + g) * 128 + j];
  }
  __syncthreads();
  for (int idx = tid; idx < 1408; idx += 192) {
    int kind, pos, r;
    if (idx < 128)       { kind = 0; pos = 0;                 r = idx; }
    else if (idx < 768)  { kind = 1; pos = (idx - 128) >> 7;  r = (idx - 128) & 127; }
    else                 { kind = 2; pos = (idx - 768) >> 7;  r = (idx - 768) & 127; }
    const int wrow = kind * 128 + r;
    const float* wr = f_wqkv + (size_t)wrow * 128;
    const float* src = P[kind == 0 ? 0 : pos];
    float s = 0.f;
    for (int j = 0; j < 128; ++j) s += src[j] * wr[j];
    s += f_bqkv[wrow];
    if (kind == 0) q0[r] = s;
    else if (kind == 1) kbuf[pos][r] = s;
    else vbuf[pos][r] = s;
  }
  __syncthreads();
  if (tid < 20) {
    int n = tid / 5, kp = tid - n * 5;
    float s = 0.f;
    for (int d = 0; d < 32; ++d) s += q0[n * 32 + d] * kbuf[kp][n * 32 + d];
    attn[n][kp] = s * 0.17677669529663687f;
  }
  __syncthreads();
  if (tid < 4) {
    float mx = -1e30f;
    for (int kp = 0; kp < 5; ++kp) mx = fmaxf(mx, attn[tid][kp]);
    float sum = 0.f;
    for (int kp = 0; kp < 5; ++kp) { float e = __expf(attn[tid][kp] - mx); attn[tid][kp] = e; sum += e; }
    float inv = 1.f / sum;
    for (int kp = 0; kp < 5; ++kp) attn[tid][kp] *= inv;
  }
  __syncthreads();
  if (tid < 128) {
    int n = tid >> 5;
    float s = 0.f;
    for (int kp = 0; kp < 5; ++kp) s += attn[n][kp] * vbuf[kp][tid];
    ao[tid] = s;
  }
  __syncthreads();
  if (tid < 128) {
    const float* wr = f_wo + (size_t)tid * 128;
    float s = 0.f;
    for (int i = 0; i < 128; ++i) s += ao[i] * wr[i];
    fin[tid] = s + f_bo[tid];
  }
  __syncthreads();
  {
    const float* wr = fc_w + (size_t)tid * 128;
    float s = 0.f;
    for (int j = 0; j < 128; ++j) s += fin[j] * wr[j];
    out[(size_t)b * 192 + tid] = s + fc_b[tid];
  }
}

// ---------------------------------------------------------------------------
extern "C" void kernel_launch(void* const* d_in, const int* in_sizes, int n_in,
                              void* d_out, int out_size, void* d_ws, size_t ws_size,
                              hipStream_t stream)
{
  const float* x      = (const float*)d_in[0];
  const float* w_ih0  = (const float*)d_in[1];
  const float* w_ih12 = (const float*)d_in[2];
  const float* w_hh   = (const float*)d_in[3];
  const float* b_ih   = (const float*)d_in[4];
  const float* b_hh   = (const float*)d_in[5];
  const float* g_wqkv = (const float*)d_in[6];
  const float* g_bqkv = (const float*)d_in[7];
  const float* g_wo   = (const float*)d_in[8];
  const float* g_bo   = (const float*)d_in[9];
  const float* f_wqkv = (const float*)d_in[10];
  const float* f_bqkv = (const float*)d_in[11];
  const float* f_wo   = (const float*)d_in[12];
  const float* f_bo   = (const float*)d_in[13];
  const float* fc_w   = (const float*)d_in[14];
  const float* fc_b   = (const float*)d_in[15];

  const size_t N_hh = (size_t)3 * NFEAT * 512 * 128;
  const size_t N_ih = (size_t)2 * NFEAT * 512 * 128;
  const size_t NB   = (size_t)3 * NFEAT * 512;
  const size_t LSL  = (size_t)NFEAT * 512 * 128;   // per-layer weight slice

  u16* Whh       = (u16*)d_ws;
  u16* Wih       = Whh + N_hh;
  float* biasAll = (float*)(Wih + N_ih);
  u16* hseq      = (u16*)(biasAll + NB);
  float* pooled  = (float*)(hseq + (size_t)NFEAT * TDIM * 32 * 128);

  prep_kernel<<<2048, 256, 0, stream>>>(w_ih12, w_hh, b_ih, b_hh, Whh, Wih, biasAll);

  lstm_layer<true, false><<<80, 512, 0, stream>>>(
      Whh, Whh /*unused*/, biasAll, x, w_ih0, hseq);
  lstm_layer<false, false><<<80, 512, 0, stream>>>(
      Whh + LSL, Wih, biasAll + NFEAT * 512, nullptr, nullptr, hseq);
  lstm_layer<false, true><<<80, 512, 0, stream>>>(
      Whh + 2 * LSL, Wih + LSL, biasAll + 2 * NFEAT * 512, nullptr, nullptr, hseq);

  gattn_kernel<<<160, 128, 0, stream>>>(hseq, g_wqkv, g_bqkv, g_wo, g_bo, pooled);
  final_kernel<<<32, 192, 0, stream>>>(pooled, f_wqkv, f_bqkv, f_wo, f_bo,
                                       fc_w, fc_b, (float*)d_out);
}